// Round 1
// baseline (109.908 us; speedup 1.0000x reference)
//
#include <hip/hip_runtime.h>
#include <hip/hip_bf16.h>

#define LOG2E 1.44269504088896340736f

__device__ __forceinline__ float fast_exp2(float x) {
#if __has_builtin(__builtin_amdgcn_exp2f)
    return __builtin_amdgcn_exp2f(x);
#else
    return exp2f(x);
#endif
}

// ---------------------------------------------------------------------------
// Stage 1: fused QKV projection with transposed outputs.
// grid = 512 blocks x 256 threads.
//   bid <  256 : Q path — rows rb*8..rb*8+7 of x   -> qT[b][h][q]
//   bid >= 256 : KV path — rows rb*8..rb*8+7 of emb -> kT[b][h][j], vT[b][h][j]
// Transposed [b,h,seq] layout makes every attention-kernel load coalesced.
// ---------------------------------------------------------------------------
__global__ __launch_bounds__(256) void proj_kernel(
    const float* __restrict__ x, const float* __restrict__ emb,
    const float* __restrict__ Wq, const float* __restrict__ Wk,
    const float* __restrict__ Wv,
    float* __restrict__ qT, float* __restrict__ kT, float* __restrict__ vT)
{
    __shared__ __align__(16) float sx[4096];    // 8 rows x 512
    __shared__ __align__(16) float sred[4096];  // partial-sum reduction buffer
    const int t   = threadIdx.x;
    const int bid = blockIdx.x;
    const bool isQ = (bid < 256);
    const int rb  = isQ ? bid : (bid - 256);

    // load 8 input rows (4096 floats), coalesced
    const float* src = (isQ ? x : emb) + (size_t)rb * 8 * 512;
    #pragma unroll
    for (int i = 0; i < 16; ++i) sx[i * 256 + t] = src[i * 256 + t];
    __syncthreads();

    const int b  = rb >> 7;          // rows rb*8 -> batch
    const int q0 = (rb << 3) & 1023; // seq offset

    if (isQ) {
        // 64 cols: thread owns col pair cp,cp+1; 8 groups split K=512 into 64-chunks
        const int cp = (t & 31) * 2;
        const int g  = t >> 5;
        const int d0 = g * 64;
        float acc0[8], acc1[8];
        #pragma unroll
        for (int r = 0; r < 8; ++r) { acc0[r] = 0.f; acc1[r] = 0.f; }
        for (int dd = 0; dd < 64; dd += 4) {
            const int d = d0 + dd;
            float2 w0 = *(const float2*)&Wq[(d + 0) * 64 + cp];
            float2 w1 = *(const float2*)&Wq[(d + 1) * 64 + cp];
            float2 w2 = *(const float2*)&Wq[(d + 2) * 64 + cp];
            float2 w3 = *(const float2*)&Wq[(d + 3) * 64 + cp];
            #pragma unroll
            for (int r = 0; r < 8; ++r) {
                float4 xv = *(const float4*)&sx[r * 512 + d];
                acc0[r] = fmaf(xv.x, w0.x, acc0[r]); acc1[r] = fmaf(xv.x, w0.y, acc1[r]);
                acc0[r] = fmaf(xv.y, w1.x, acc0[r]); acc1[r] = fmaf(xv.y, w1.y, acc1[r]);
                acc0[r] = fmaf(xv.z, w2.x, acc0[r]); acc1[r] = fmaf(xv.z, w2.y, acc1[r]);
                acc0[r] = fmaf(xv.w, w3.x, acc0[r]); acc1[r] = fmaf(xv.w, w3.y, acc1[r]);
            }
        }
        #pragma unroll
        for (int r = 0; r < 8; ++r)
            *(float2*)&sred[g * 512 + r * 64 + cp] = make_float2(acc0[r], acc1[r]);
        __syncthreads();
        #pragma unroll
        for (int p = 0; p < 2; ++p) {
            int idx = p * 256 + t;
            int r = idx >> 6, h = idx & 63;
            float s = 0.f;
            #pragma unroll
            for (int g2 = 0; g2 < 8; ++g2) s += sred[g2 * 512 + r * 64 + h];
            qT[(size_t)(b * 64 + h) * 1024 + q0 + r] = s;
        }
    } else {
        // 128 cols (64 K + 64 V): col pair cp,cp+1; 4 groups split K=512 into 128-chunks
        const int cp = (t & 63) * 2;
        const int g  = t >> 6;
        const int d0 = g * 128;
        const float* Wsel = (cp < 64) ? (Wk + cp) : (Wv + (cp - 64));
        float acc0[8], acc1[8];
        #pragma unroll
        for (int r = 0; r < 8; ++r) { acc0[r] = 0.f; acc1[r] = 0.f; }
        for (int dd = 0; dd < 128; dd += 4) {
            const int d = d0 + dd;
            float2 w0 = *(const float2*)&Wsel[(d + 0) * 64];
            float2 w1 = *(const float2*)&Wsel[(d + 1) * 64];
            float2 w2 = *(const float2*)&Wsel[(d + 2) * 64];
            float2 w3 = *(const float2*)&Wsel[(d + 3) * 64];
            #pragma unroll
            for (int r = 0; r < 8; ++r) {
                float4 xv = *(const float4*)&sx[r * 512 + d];
                acc0[r] = fmaf(xv.x, w0.x, acc0[r]); acc1[r] = fmaf(xv.x, w0.y, acc1[r]);
                acc0[r] = fmaf(xv.y, w1.x, acc0[r]); acc1[r] = fmaf(xv.y, w1.y, acc1[r]);
                acc0[r] = fmaf(xv.z, w2.x, acc0[r]); acc1[r] = fmaf(xv.z, w2.y, acc1[r]);
                acc0[r] = fmaf(xv.w, w3.x, acc0[r]); acc1[r] = fmaf(xv.w, w3.y, acc1[r]);
            }
        }
        #pragma unroll
        for (int r = 0; r < 8; ++r)
            *(float2*)&sred[g * 1024 + r * 128 + cp] = make_float2(acc0[r], acc1[r]);
        __syncthreads();
        #pragma unroll
        for (int p = 0; p < 4; ++p) {
            int idx = p * 256 + t;
            int r = idx >> 7, c = idx & 127;
            float s = 0.f;
            #pragma unroll
            for (int g2 = 0; g2 < 4; ++g2) s += sred[g2 * 1024 + r * 128 + c];
            if (c < 64) kT[(size_t)(b * 64 + c) * 1024 + q0 + r] = s;
            else        vT[(size_t)(b * 64 + (c - 64)) * 1024 + q0 + r] = s;
        }
    }
}

// ---------------------------------------------------------------------------
// Stage 2: attention. head_dim==1 => per (b,h): o[q] = sum_j e(q_s*k_j) v_j / sum_j e(..).
// grid = B*64*4 = 512 blocks (b, h, q-chunk of 256), 256 threads (one q each).
// k/v columns staged in LDS; inner-loop LDS reads are same-address broadcasts.
// Exact softmax stabilization via block-wide kmax/kmin.
// ---------------------------------------------------------------------------
__global__ __launch_bounds__(256) void attn_kernel(
    const float* __restrict__ qT, const float* __restrict__ kT,
    const float* __restrict__ vT, float* __restrict__ O)
{
    __shared__ __align__(16) float kc[1024];
    __shared__ __align__(16) float vc[1024];
    __shared__ float wred[8];
    const int t   = threadIdx.x;
    const int bid = blockIdx.x;
    const int b   = bid >> 8;
    const int h   = (bid >> 2) & 63;
    const int qc  = bid & 3;
    const size_t base = (size_t)(b * 64 + h) * 1024;

    float kmx = -1e30f, kmn = 1e30f;
    #pragma unroll
    for (int i = 0; i < 4; ++i) {
        float kv = kT[base + i * 256 + t];
        float vv = vT[base + i * 256 + t];
        kc[i * 256 + t] = kv;
        vc[i * 256 + t] = vv;
        kmx = fmaxf(kmx, kv);
        kmn = fminf(kmn, kv);
    }
    #pragma unroll
    for (int off = 32; off >= 1; off >>= 1) {
        kmx = fmaxf(kmx, __shfl_xor(kmx, off));
        kmn = fminf(kmn, __shfl_xor(kmn, off));
    }
    const int wid = t >> 6;
    if ((t & 63) == 0) { wred[wid] = kmx; wred[4 + wid] = kmn; }
    __syncthreads();
    kmx = fmaxf(fmaxf(wred[0], wred[1]), fmaxf(wred[2], wred[3]));
    kmn = fminf(fminf(wred[4], wred[5]), fminf(wred[6], wred[7]));

    const float qs = qT[base + qc * 256 + t];           // coalesced
    const float m  = (qs >= 0.f) ? qs * kmx : qs * kmn; // exact row max of scores
    const float a  = qs * LOG2E;
    const float bb = -m * LOG2E;

    float d0 = 0.f, d1 = 0.f, d2 = 0.f, d3 = 0.f;
    float n0 = 0.f, n1 = 0.f, n2 = 0.f, n3 = 0.f;
    const float4* kc4 = (const float4*)kc;
    const float4* vc4 = (const float4*)vc;
    for (int j = 0; j < 256; ++j) {
        float4 k4 = kc4[j];
        float4 v4 = vc4[j];
        float e0 = fast_exp2(fmaf(a, k4.x, bb));
        float e1 = fast_exp2(fmaf(a, k4.y, bb));
        float e2 = fast_exp2(fmaf(a, k4.z, bb));
        float e3 = fast_exp2(fmaf(a, k4.w, bb));
        d0 += e0; n0 = fmaf(e0, v4.x, n0);
        d1 += e1; n1 = fmaf(e1, v4.y, n1);
        d2 += e2; n2 = fmaf(e2, v4.z, n2);
        d3 += e3; n3 = fmaf(e3, v4.w, n3);
    }
    const float den = (d0 + d1) + (d2 + d3);
    const float num = (n0 + n1) + (n2 + n3);
    const int q = qc * 256 + t;
    O[(size_t)(b * 1024 + q) * 64 + h] = num / den;   // [b,q,h] layout for stage 3
}

// ---------------------------------------------------------------------------
// Stage 3: out = O @ Wo + bo.  [2048x64]@[64x512].
// grid = 256 blocks (8 rows each), 256 threads (2 output cols each).
// ---------------------------------------------------------------------------
__global__ __launch_bounds__(256) void oproj_kernel(
    const float* __restrict__ O, const float* __restrict__ Wo,
    const float* __restrict__ bo, float* __restrict__ out)
{
    __shared__ __align__(16) float so[512];   // 8 rows x 64
    const int t  = threadIdx.x;
    const int rb = blockIdx.x;
    const size_t r0 = (size_t)rb * 8;
    so[t]       = O[r0 * 64 + t];
    so[t + 256] = O[r0 * 64 + t + 256];
    __syncthreads();

    const int d2 = t * 2;
    float2 bv = *(const float2*)&bo[d2];
    float acc0[8], acc1[8];
    #pragma unroll
    for (int r = 0; r < 8; ++r) { acc0[r] = bv.x; acc1[r] = bv.y; }
    for (int hh = 0; hh < 64; hh += 4) {
        float2 w0 = *(const float2*)&Wo[(hh + 0) * 512 + d2];
        float2 w1 = *(const float2*)&Wo[(hh + 1) * 512 + d2];
        float2 w2 = *(const float2*)&Wo[(hh + 2) * 512 + d2];
        float2 w3 = *(const float2*)&Wo[(hh + 3) * 512 + d2];
        #pragma unroll
        for (int r = 0; r < 8; ++r) {
            float4 s4 = *(const float4*)&so[r * 64 + hh];
            acc0[r] = fmaf(s4.x, w0.x, acc0[r]); acc1[r] = fmaf(s4.x, w0.y, acc1[r]);
            acc0[r] = fmaf(s4.y, w1.x, acc0[r]); acc1[r] = fmaf(s4.y, w1.y, acc1[r]);
            acc0[r] = fmaf(s4.z, w2.x, acc0[r]); acc1[r] = fmaf(s4.z, w2.y, acc1[r]);
            acc0[r] = fmaf(s4.w, w3.x, acc0[r]); acc1[r] = fmaf(s4.w, w3.y, acc1[r]);
        }
    }
    #pragma unroll
    for (int r = 0; r < 8; ++r)
        *(float2*)&out[(r0 + r) * 512 + d2] = make_float2(acc0[r], acc1[r]);
}

extern "C" void kernel_launch(void* const* d_in, const int* in_sizes, int n_in,
                              void* d_out, int out_size, void* d_ws, size_t ws_size,
                              hipStream_t stream)
{
    const float* x   = (const float*)d_in[0];
    const float* emb = (const float*)d_in[1];
    const float* Wq  = (const float*)d_in[2];
    const float* Wk  = (const float*)d_in[3];
    const float* Wv  = (const float*)d_in[4];
    const float* Wo  = (const float*)d_in[5];
    const float* bo  = (const float*)d_in[6];
    float* out = (float*)d_out;

    // workspace: qT/kT/vT [B,64,1024] transposed + O [B,1024,64] — 2 MB total
    float* qT = (float*)d_ws;
    float* kT = qT + 131072;
    float* vT = kT + 131072;
    float* O  = vT + 131072;

    proj_kernel<<<512, 256, 0, stream>>>(x, emb, Wq, Wk, Wv, qT, kT, vT);
    attn_kernel<<<512, 256, 0, stream>>>(qT, kT, vT, O);
    oproj_kernel<<<256, 256, 0, stream>>>(O, Wo, bo, out);
}